// Round 5
// baseline (371.948 us; speedup 1.0000x reference)
//
#include <hip/hip_runtime.h>
#include <math.h>

// ---------------------------------------------------------------------------
// (B, Cin, Cout, Rout, N1, N2) = (8, 256, 512, 256, 4096, 1024)
// Activations token-major X[b][n][c] (c contiguous) except v [c][m].
// LN/softmax normalizations are fused: producer GEMM epilogue emits per-row
// stats atomically; consumer GEMM applies the transform while staging.
// ---------------------------------------------------------------------------

typedef __attribute__((ext_vector_type(8))) short short8x;
typedef __attribute__((ext_vector_type(4))) float f32x4;

__device__ __forceinline__ unsigned short f2b(float f) {
  unsigned int u = __float_as_uint(f);
  unsigned int r = u + 0x7FFFu + ((u >> 16) & 1u);
  return (unsigned short)(r >> 16);
}
__device__ __forceinline__ float b2f(unsigned short h) {
  return __uint_as_float(((unsigned int)h) << 16);
}

__device__ __forceinline__ void cp16(const unsigned short* g, unsigned short* l) {
  __builtin_amdgcn_global_load_lds(
      (const __attribute__((address_space(1))) void*)g,
      (__attribute__((address_space(3))) void*)l, 16, 0, 0);
}

// ===========================================================================
// conv_weights (y=0..6) merged with sel_qw (y=7, x<8).
// ===========================================================================
__global__ void __launch_bounds__(256) prep_kernel(
    const float* w0, const float* w1, const float* w2, const float* w3,
    const float* w4, const float* w5, const float* w6,
    unsigned short* d0, unsigned short* d1, unsigned short* d2,
    unsigned short* d3, unsigned short* d4, unsigned short* d5,
    unsigned short* d6,
    const float* __restrict__ l1, const float* __restrict__ q1w,
    const float* __restrict__ k1w, float* __restrict__ wvec) {
  if (blockIdx.y == 7) {
    if (blockIdx.x >= 8) return;
    const int b = blockIdx.x;
    const int t = threadIdx.x;
    __shared__ float col[256];
    __shared__ float q1v[512];
    col[t] = l1[(long)b * 256 * 4096 + (long)t * 4096];
    __syncthreads();
    for (int o = t; o < 512; o += 256) {
      float s = 0.f;
      const float* row = q1w + (long)o * 256;
      for (int c = 0; c < 256; ++c) s += row[c] * col[c];
      q1v[o] = s;
    }
    __syncthreads();
    float s = 0.f;
    for (int o = 0; o < 512; ++o) s += k1w[(long)o * 256 + t] * q1v[o];
    wvec[b * 256 + t] = s;
    return;
  }
  const float* src;
  unsigned short* dst;
  int n;
  switch (blockIdx.y) {
    case 0: src = w0; dst = d0; n = 65536; break;
    case 1: src = w1; dst = d1; n = 131072; break;
    case 2: src = w2; dst = d2; n = 262144; break;
    case 3: src = w3; dst = d3; n = 262144; break;
    case 4: src = w4; dst = d4; n = 262144; break;
    case 5: src = w5; dst = d5; n = 262144; break;
    default: src = w6; dst = d6; n = 131072; break;
  }
  const int i = (blockIdx.x * 256 + threadIdx.x) * 4;
  if (i < n) {
    const float4 v = *(const float4*)(src + i);
    ushort4 o;
    o.x = f2b(v.x); o.y = f2b(v.y); o.z = f2b(v.z); o.w = f2b(v.w);
    *(ushort4*)(dst + i) = o;
  }
}

// ===========================================================================
// scores[b,m] = sum_c wvec[b,c] * l1[b,c,m]   (f32 exact)
// ===========================================================================
__global__ void __launch_bounds__(256) sel_scores_kernel(
    const float* __restrict__ l1, const float* __restrict__ wvec,
    float* __restrict__ scores) {
  const int b = blockIdx.y;
  const int m = blockIdx.x * 256 + threadIdx.x;
  __shared__ float w[256];
  w[threadIdx.x] = wvec[b * 256 + threadIdx.x];
  __syncthreads();
  const float* base = l1 + (long)b * 256 * 4096 + m;
  float s = 0.f;
  for (int c = 0; c < 256; ++c) s += w[c] * base[(long)c * 4096];
  scores[b * 4096 + m] = s;
}

// ===========================================================================
// Exact top-1024 SET per batch (radix select), output index-sorted ascending.
// ===========================================================================
__global__ void __launch_bounds__(256) topk_select_kernel(
    const float* __restrict__ scores, int* __restrict__ idx_out) {
  const int b = blockIdx.x;
  const int t = threadIdx.x;
  __shared__ unsigned int keys[4096];
  __shared__ unsigned int hist[256];
  __shared__ unsigned int sc_prefix, sc_krem;
  __shared__ int s_bin;
  __shared__ unsigned int partial_gt[256], partial_eq[256];

  for (int m = t; m < 4096; m += 256) {
    unsigned int u = __float_as_uint(scores[b * 4096 + m]);
    u ^= (u & 0x80000000u) ? 0xFFFFFFFFu : 0x80000000u;
    keys[m] = u;
  }
  if (t == 0) { sc_prefix = 0u; sc_krem = 1024u; }
  __syncthreads();

  unsigned int prefmask = 0u;
  for (int shift = 24; shift >= 0; shift -= 8) {
    hist[t] = 0u;
    if (t == 0) s_bin = 0;
    __syncthreads();
    const unsigned int prefix = sc_prefix;
    for (int m = t; m < 4096; m += 256) {
      unsigned int key = keys[m];
      if ((key & prefmask) == prefix) atomicAdd(&hist[(key >> shift) & 255u], 1u);
    }
    __syncthreads();
    for (int off = 1; off < 256; off <<= 1) {
      unsigned int v = hist[t] + ((t + off < 256) ? hist[t + off] : 0u);
      __syncthreads();
      hist[t] = v;
      __syncthreads();
    }
    const unsigned int krem = sc_krem;
    if (hist[t] >= krem) atomicMax(&s_bin, t);
    __syncthreads();
    if (t == 0) {
      const int bin = s_bin;
      sc_krem = krem - ((bin < 255) ? hist[bin + 1] : 0u);
      sc_prefix = prefix | ((unsigned int)bin << shift);
    }
    prefmask |= (0xFFu << shift);
    __syncthreads();
  }
  const unsigned int cutoff = sc_prefix;
  const unsigned int need = sc_krem;

  unsigned int gt = 0u, eq = 0u;
  const int base = t * 16;
  for (int i = 0; i < 16; ++i) {
    unsigned int key = keys[base + i];
    gt += (key > cutoff);
    eq += (key == cutoff);
  }
  partial_gt[t] = gt;
  partial_eq[t] = eq;
  __syncthreads();
  for (int off = 1; off < 256; off <<= 1) {
    unsigned int g = partial_gt[t] + ((t >= off) ? partial_gt[t - off] : 0u);
    unsigned int e2 = partial_eq[t] + ((t >= off) ? partial_eq[t - off] : 0u);
    __syncthreads();
    partial_gt[t] = g;
    partial_eq[t] = e2;
    __syncthreads();
  }
  const unsigned int pref_gt = partial_gt[t] - gt;
  const unsigned int pref_eq = partial_eq[t] - eq;
  unsigned int pos = pref_gt + ((pref_eq < need) ? pref_eq : need);
  unsigned int eqr = pref_eq;
  for (int i = 0; i < 16; ++i) {
    unsigned int key = keys[base + i];
    bool sel = (key > cutoff);
    if (key == cutoff) sel = sel || (eqr++ < need);
    if (sel) idx_out[b * 1024 + (pos++)] = base + i;
  }
}

// ===========================================================================
// Gather (idx ascending): l1selT[b][j][c] bf16 token-major, p1selT f32.
// ===========================================================================
__global__ void __launch_bounds__(256) gather_sel_kernel(
    const float* __restrict__ l1, const float* __restrict__ xyz1,
    const int* __restrict__ idx, unsigned short* __restrict__ l1selT,
    float* __restrict__ p1selT) {
  const int b = blockIdx.z;
  const int j = blockIdx.x * 64 + (threadIdx.x & 63);
  const int cz = blockIdx.y;
  const int cg = threadIdx.x >> 6;
  const int ix = idx[b * 1024 + j];
  const float* src = l1 + (long)b * 256 * 4096 + ix;
  unsigned short* dst = l1selT + ((long)b * 1024 + j) * 256;
#pragma unroll
  for (int it = 0; it < 8; ++it) {
    const int c = cz * 128 + it * 16 + cg * 4;
    const float x0 = src[(long)(c + 0) * 4096];
    const float x1 = src[(long)(c + 1) * 4096];
    const float x2 = src[(long)(c + 2) * 4096];
    const float x3 = src[(long)(c + 3) * 4096];
    ushort4 o;
    o.x = f2b(x0); o.y = f2b(x1); o.z = f2b(x2); o.w = f2b(x3);
    *(ushort4*)&dst[c] = o;
  }
  if (cz == 0 && cg == 0) {
    float* dp = p1selT + ((long)b * 1024 + j) * 3;
#pragma unroll
    for (int d = 0; d < 3; ++d) dp[d] = xyz1[((long)b * 3 + d) * 4096 + ix];
  }
}

// ===========================================================================
// Transpose l2 -> token-major + pos_q; l2T f32 residual copy.
// ===========================================================================
__global__ void __launch_bounds__(256) transpose_posq_kernel(
    const float* __restrict__ l2, const float* __restrict__ xyz2,
    const float* __restrict__ posw, unsigned short* __restrict__ qinT,
    float* __restrict__ l2T) {
  const int b = blockIdx.z;
  const int n0 = blockIdx.x * 64, c0 = blockIdx.y * 64;
  const int tx = threadIdx.x, ty = threadIdx.y;
  __shared__ float tile[64][65];
  __shared__ float sx[3][64];
  const float* l2b = l2 + (long)b * 512 * 1024;
  for (int r = 0; r < 16; ++r) {
    const int c = ty * 16 + r;
    tile[c][tx] = l2b[(long)(c0 + c) * 1024 + n0 + tx];
  }
  if (ty < 3) sx[ty][tx] = xyz2[((long)b * 3 + ty) * 1024 + n0 + tx];
  __syncthreads();
  const int c = c0 + tx;
  const float p0 = posw[c * 3], p1 = posw[c * 3 + 1], p2 = posw[c * 3 + 2];
  for (int r = 0; r < 16; ++r) {
    const int nl = ty * 16 + r;
    const float val = tile[tx][nl];
    const long o = ((long)b * 1024 + n0 + nl) * 512 + c;
    l2T[o] = val;
    qinT[o] = f2b(val + p0 * sx[0][nl] + p1 * sx[1][nl] + p2 * sx[2][nl]);
  }
}

// ===========================================================================
// kinT[n][c] bf16 = x2T[n][c] + posw[c]·p1selT[n][:]
// ===========================================================================
__global__ void __launch_bounds__(128) kin_kernel(
    const unsigned short* __restrict__ x2T, const float* __restrict__ p1selT,
    const float* __restrict__ posw, unsigned short* __restrict__ kinT) {
  const long row = blockIdx.x;
  const int t = threadIdx.x;
  const float q0 = p1selT[row * 3], q1 = p1selT[row * 3 + 1], q2 = p1selT[row * 3 + 2];
  const int c = t * 4;
  const ushort4 xv = *(const ushort4*)&x2T[row * 512 + c];
  ushort4 o;
  o.x = f2b(b2f(xv.x) + posw[(c + 0) * 3] * q0 + posw[(c + 0) * 3 + 1] * q1 + posw[(c + 0) * 3 + 2] * q2);
  o.y = f2b(b2f(xv.y) + posw[(c + 1) * 3] * q0 + posw[(c + 1) * 3 + 1] * q1 + posw[(c + 1) * 3 + 2] * q2);
  o.z = f2b(b2f(xv.z) + posw[(c + 2) * 3] * q0 + posw[(c + 2) * 3 + 1] * q1 + posw[(c + 2) * 3 + 2] * q2);
  o.w = f2b(b2f(xv.w) + posw[(c + 3) * 3] * q0 + posw[(c + 3) * 3 + 1] * q1 + posw[(c + 3) * 3 + 2] * q2);
  *(ushort4*)&kinT[row * 512 + c] = o;
}

// ===========================================================================
// Unified MFMA bf16 GEMM.  D = alpha*A[M][K]·Bt[N][K]^T (+bias)(+res)
// 128x128 tile, 4 waves, BK=32 double-buffered, cp16 staging, XOR swizzle.
// TRA/TRB: 1 => that operand is LN(+act)-transformed while staging
//          (row stats from ts1/ts2, scale tg, shift tb, leaky slope tslope).
// EPI: 0 f32 out | 1 bf16 out | 2 bf16 out + row LN-stats (os1,os2)
//    | 3 p=exp(alpha*acc) bf16 out + row sum (os1)
//    | 4 bf16 out, acc scaled by 1/ts1[row] (+res), + row LN-stats
// ===========================================================================
template <int TRA, int TRB, bool BCOL, bool BROW, bool RES, int EPI>
__global__ void __launch_bounds__(256) gemm_u(
    const unsigned short* __restrict__ A, long sA, int ldA,
    const unsigned short* __restrict__ Bt, long sB, int ldB, long sB8,
    void* __restrict__ Yv, long sY, int ldY,
    const float* __restrict__ bias,
    const float* __restrict__ res, long sR,
    int K, float alpha,
    const float* __restrict__ ts1, const float* __restrict__ ts2,
    const float* __restrict__ tg, const float* __restrict__ tb, float tslope,
    float* __restrict__ os1, float* __restrict__ os2) {
  __shared__ __align__(16) unsigned short ldsA[2][128 * 32];
  __shared__ __align__(16) unsigned short ldsB[2][128 * 32];
  const int tid = threadIdx.x;
  const int lane = tid & 63;
  const int wv = tid >> 6;
  const int wm = wv >> 1, wn = wv & 1;
  const int n0 = blockIdx.x * 128, m0 = blockIdx.y * 128, b = blockIdx.z;
  A += (long)b * sA;
  Bt += (long)(b & 7) * sB + (long)(b >> 3) * sB8;
  const int lane15 = lane & 15, q = lane >> 4;

  // cp16 staging addresses
  const int srow0 = wv * 32 + (lane >> 2);
  const int srow1 = srow0 + 16;
  const int ks0 = ((lane & 3) ^ ((srow0 >> 1) & 3)) << 3;
  const int ks1 = ((lane & 3) ^ ((srow1 >> 1) & 3)) << 3;
  const unsigned short* gA0 = A + (long)(m0 + srow0) * ldA + ks0;
  const unsigned short* gA1 = A + (long)(m0 + srow1) * ldA + ks1;
  const unsigned short* gB0 = Bt + (long)(n0 + srow0) * ldB + ks0;
  const unsigned short* gB1 = Bt + (long)(n0 + srow1) * ldB + ks1;
  unsigned short* lA0[2] = {&ldsA[0][(wv * 32) * 32], &ldsA[1][(wv * 32) * 32]};
  unsigned short* lA1[2] = {&ldsA[0][(wv * 32 + 16) * 32], &ldsA[1][(wv * 32 + 16) * 32]};
  unsigned short* lB0[2] = {&ldsB[0][(wv * 32) * 32], &ldsB[1][(wv * 32) * 32]};
  unsigned short* lB1[2] = {&ldsB[0][(wv * 32 + 16) * 32], &ldsB[1][(wv * 32 + 16) * 32]};

  // transform staging setup (LN while writing LDS)
  constexpr bool TR = (TRA + TRB) != 0;
  const int trow = tid & 127, thalf = tid >> 7;
  float t_mu = 0.f, t_rs = 0.f;
  const unsigned short* tsrc = nullptr;
  int toff0 = 0, toff1 = 0;
  if constexpr (TR) {
    const int row0 = (TRA ? m0 : n0) + trow;
    const int ridx = (b & 7) * 1024 + row0;
    const float Cf = (float)K;
    const float s1v = ts1[ridx], s2v = ts2[ridx];
    t_mu = s1v / Cf;
    t_rs = rsqrtf(s2v / Cf - t_mu * t_mu + 1e-5f);
    tsrc = (TRA ? A + (long)row0 * ldA : Bt + (long)row0 * ldB) + thalf * 16;
    const int sw = (trow >> 1) & 3;
    toff0 = trow * 32 + ((((thalf * 2) ^ sw)) << 3);
    toff1 = trow * 32 + ((((thalf * 2 + 1) ^ sw)) << 3);
  }

  auto t_apply = [&](int kk, short8x r0, short8x r1, int buf) {
    union { short8x v; unsigned short u[8]; } a0, a1, w0, w1;
    a0.v = r0; a1.v = r1;
    const float4* gp = (const float4*)(tg + kk + thalf * 16);
    const float4* bp = (const float4*)(tb + kk + thalf * 16);
    const float4 g0 = gp[0], g1 = gp[1], g2 = gp[2], g3 = gp[3];
    const float4 e0 = bp[0], e1 = bp[1], e2 = bp[2], e3 = bp[3];
    const float gg[16] = {g0.x, g0.y, g0.z, g0.w, g1.x, g1.y, g1.z, g1.w,
                          g2.x, g2.y, g2.z, g2.w, g3.x, g3.y, g3.z, g3.w};
    const float ee[16] = {e0.x, e0.y, e0.z, e0.w, e1.x, e1.y, e1.z, e1.w,
                          e2.x, e2.y, e2.z, e2.w, e3.x, e3.y, e3.z, e3.w};
#pragma unroll
    for (int c = 0; c < 8; ++c) {
      float y = (b2f(a0.u[c]) - t_mu) * t_rs * gg[c] + ee[c];
      y = y > 0.f ? y : tslope * y;
      w0.u[c] = f2b(y);
    }
#pragma unroll
    for (int c = 0; c < 8; ++c) {
      float y = (b2f(a1.u[c]) - t_mu) * t_rs * gg[8 + c] + ee[8 + c];
      y = y > 0.f ? y : tslope * y;
      w1.u[c] = f2b(y);
    }
    unsigned short* base = TRA ? &ldsA[buf][0] : &ldsB[buf][0];
    *(short8x*)&base[toff0] = w0.v;
    *(short8x*)&base[toff1] = w1.v;
  };

  // prologue
  short8x tr0, tr1;
  if constexpr (TR) {
    tr0 = *(const short8x*)(tsrc + 0);
    tr1 = *(const short8x*)(tsrc + 8);
  }
  if constexpr (!TRA) { cp16(gA0, lA0[0]); cp16(gA1, lA1[0]); }
  if constexpr (!TRB) { cp16(gB0, lB0[0]); cp16(gB1, lB1[0]); }
  if constexpr (TR) t_apply(0, tr0, tr1, 0);

  f32x4 acc[4][4] = {};
  int cur = 0;
  for (int k0 = 0; k0 < K; k0 += 32) {
    __syncthreads();
    const bool nxt = (k0 + 32 < K);
    if (nxt) {
      const int nk = k0 + 32;
      if constexpr (!TRA) { cp16(gA0 + nk, lA0[cur ^ 1]); cp16(gA1 + nk, lA1[cur ^ 1]); }
      if constexpr (!TRB) { cp16(gB0 + nk, lB0[cur ^ 1]); cp16(gB1 + nk, lB1[cur ^ 1]); }
      if constexpr (TR) {
        tr0 = *(const short8x*)(tsrc + nk);
        tr1 = *(const short8x*)(tsrc + nk + 8);
      }
    }
    short8x af[4], bfr[4];
#pragma unroll
    for (int i = 0; i < 4; ++i) {
      const int m = wm * 64 + i * 16 + lane15;
      af[i] = *(const short8x*)&ldsA[cur][m * 32 + ((q ^ ((m >> 1) & 3)) << 3)];
      const int n = wn * 64 + i * 16 + lane15;
      bfr[i] = *(const short8x*)&ldsB[cur][n * 32 + ((q ^ ((n >> 1) & 3)) << 3)];
    }
#pragma unroll
    for (int i = 0; i < 4; ++i)
#pragma unroll
      for (int j = 0; j < 4; ++j)
        acc[i][j] = __builtin_amdgcn_mfma_f32_16x16x32_bf16(af[i], bfr[j], acc[i][j], 0, 0, 0);
    if (nxt) {
      if constexpr (TR) t_apply(k0 + 32, tr0, tr1, cur ^ 1);
    }
    cur ^= 1;
  }

  // epilogue
  float* Yf = (float*)Yv;
  unsigned short* Yh = (unsigned short*)Yv;
  if constexpr (EPI == 0) Yf += (long)b * sY; else Yh += (long)b * sY;
  if constexpr (RES) res += (long)b * sR;
  float inv_[4];
  float ssum[4][4], ssq[4][4];
#pragma unroll
  for (int i = 0; i < 4; ++i)
#pragma unroll
    for (int r = 0; r < 4; ++r) { ssum[i][r] = 0.f; ssq[i][r] = 0.f; }

#pragma unroll
  for (int i = 0; i < 4; ++i) {
    if constexpr (EPI == 4) {
#pragma unroll
      for (int r = 0; r < 4; ++r)
        inv_[r] = 1.f / ts1[(b & 7) * 1024 + m0 + wm * 64 + i * 16 + q * 4 + r];
    }
#pragma unroll
    for (int j = 0; j < 4; ++j) {
      const int n_g = n0 + wn * 64 + j * 16 + lane15;
      const float bc = BCOL ? bias[n_g] : 0.f;
#pragma unroll
      for (int r = 0; r < 4; ++r) {
        const int m_g = m0 + wm * 64 + i * 16 + q * 4 + r;
        float y = acc[i][j][r] * alpha;
        if constexpr (EPI == 4) y *= inv_[r];
        if constexpr (BCOL) y += bc;
        if constexpr (BROW) y += bias[m_g];
        if constexpr (RES) y += res[(long)m_g * ldY + n_g];
        if constexpr (EPI == 3) y = __expf(y);
        const long off = (long)m_g * ldY + n_g;
        if constexpr (EPI == 0) Yf[off] = y;
        else Yh[off] = f2b(y);
        if constexpr (EPI >= 2) { ssum[i][r] += y; ssq[i][r] += y * y; }
      }
    }
  }
  if constexpr (EPI == 2 || EPI == 4) {
#pragma unroll
    for (int i = 0; i < 4; ++i)
#pragma unroll
      for (int r = 0; r < 4; ++r) {
        float s = ssum[i][r], q2 = ssq[i][r];
        s += __shfl_xor(s, 1); q2 += __shfl_xor(q2, 1);
        s += __shfl_xor(s, 2); q2 += __shfl_xor(q2, 2);
        s += __shfl_xor(s, 4); q2 += __shfl_xor(q2, 4);
        s += __shfl_xor(s, 8); q2 += __shfl_xor(q2, 8);
        if (lane15 == 0) {
          const int ridx = (b & 7) * 1024 + m0 + wm * 64 + i * 16 + q * 4 + r;
          atomicAdd(&os1[ridx], s);
          atomicAdd(&os2[ridx], q2);
        }
      }
  } else if constexpr (EPI == 3) {
#pragma unroll
    for (int i = 0; i < 4; ++i)
#pragma unroll
      for (int r = 0; r < 4; ++r) {
        float s = ssum[i][r];
        s += __shfl_xor(s, 1);
        s += __shfl_xor(s, 2);
        s += __shfl_xor(s, 4);
        s += __shfl_xor(s, 8);
        if (lane15 == 0) {
          const int ridx = (b & 7) * 1024 + m0 + wm * 64 + i * 16 + q * 4 + r;
          atomicAdd(&os1[ridx], s);
        }
      }
  }
}

// ===========================================================================
// Launch
// ===========================================================================
extern "C" void kernel_launch(void* const* d_in, const int* in_sizes, int n_in,
                              void* d_out, int out_size, void* d_ws,
                              size_t ws_size, hipStream_t stream) {
  const float* l1 = (const float*)d_in[0];
  const float* xyz1 = (const float*)d_in[1];
  const float* l2 = (const float*)d_in[2];
  const float* xyz2 = (const float*)d_in[3];
  const float* q1w = (const float*)d_in[4];
  const float* k1w = (const float*)d_in[5];
  const float* mlp_w1 = (const float*)d_in[6];
  const float* mlp_b1 = (const float*)d_in[7];
  const float* mlp_g1 = (const float*)d_in[8];
  const float* mlp_be1 = (const float*)d_in[9];
  const float* mlp_w2 = (const float*)d_in[10];
  const float* mlp_b2 = (const float*)d_in[11];
  const float* qw = (const float*)d_in[12];
  const float* kw = (const float*)d_in[13];
  const float* vw = (const float*)d_in[14];
  const float* posw = (const float*)d_in[15];
  const float* norm_g = (const float*)d_in[16];
  const float* norm_b = (const float*)d_in[17];
  const float* m1_w1 = (const float*)d_in[18];
  const float* m1_b1 = (const float*)d_in[19];
  const float* m1_g = (const float*)d_in[20];
  const float* m1_be = (const float*)d_in[21];
  const float* m1_w2 = (const float*)d_in[22];
  const float* m1_b2 = (const float*)d_in[23];

  char* ws = (char*)d_ws;
  const long MiB = 1048576;
  unsigned short* wb_mlp_w1 = (unsigned short*)(ws + 0);
  unsigned short* wb_mlp_w2 = (unsigned short*)(ws + 131072);
  unsigned short* wb_qw = (unsigned short*)(ws + 393216);
  unsigned short* wb_kw = (unsigned short*)(ws + 917504);   // = wb_qw + 512KB
  unsigned short* wb_vw = (unsigned short*)(ws + 1441792);
  unsigned short* wb_m1w1 = (unsigned short*)(ws + 1966080);
  unsigned short* wb_m1w2 = (unsigned short*)(ws + 2490368);
  float* scores = (float*)(ws + 2752512);
  float* wvec = (float*)(ws + 2883584);
  int* idxb = (int*)(ws + 2891776);
  float* p1selT = (float*)(ws + 2924544);
  // stats (zeroed): 7 x 32 KB
  float* rowsum = (float*)(ws + 3407872);
  float* h1_s1 = (float*)(ws + 3440640);
  float* h1_s2 = (float*)(ws + 3473408);
  float* o_s1 = (float*)(ws + 3506176);
  float* o_s2 = (float*)(ws + 3538944);
  float* g1_s1 = (float*)(ws + 3571712);
  float* g1_s2 = (float*)(ws + 3604480);
  // big buffers (bf16 unless noted)
  unsigned short* l1selT = (unsigned short*)(ws + 4 * MiB);   // [4,8)
  unsigned short* h1 = (unsigned short*)(ws + 8 * MiB);       // [8,12)
  unsigned short* x2T = (unsigned short*)(ws + 12 * MiB);     // [12,20)
  unsigned short* qinT = (unsigned short*)(ws + 20 * MiB);    // [20,28)
  unsigned short* kinT = (unsigned short*)(ws + 28 * MiB);    // [28,36) contiguous
  float* l2T = (float*)(ws + 36 * MiB);                       // [36,52) f32
  unsigned short* qT = (unsigned short*)(ws + 52 * MiB);      // [52,60)
  unsigned short* kT = (unsigned short*)(ws + 60 * MiB);      // [60,68) contiguous
  unsigned short* vbf = (unsigned short*)(ws + 68 * MiB);     // [68,76)
  unsigned short* pbuf = (unsigned short*)(ws + 76 * MiB);    // [76,92)
  unsigned short* obuf = (unsigned short*)(ws + 92 * MiB);    // [92,100)
  unsigned short* g1buf = (unsigned short*)(ws + 100 * MiB);  // [100,108)
  float* outp = (float*)d_out;

  const float inv_scale = 1.0f / sqrtf(512.0f);
  const long T256 = 1024L * 256, T512 = 1024L * 512, T1024 = 1024L * 1024;

  hipMemsetAsync(ws + 3407872, 0, 7 * 32768, stream);

  prep_kernel<<<dim3(256, 8), 256, 0, stream>>>(
      mlp_w1, mlp_w2, qw, kw, vw, m1_w1, m1_w2,
      wb_mlp_w1, wb_mlp_w2, wb_qw, wb_kw, wb_vw, wb_m1w1, wb_m1w2,
      l1, q1w, k1w, wvec);
  sel_scores_kernel<<<dim3(16, 8), 256, 0, stream>>>(l1, wvec, scores);
  topk_select_kernel<<<8, 256, 0, stream>>>(scores, idxb);
  gather_sel_kernel<<<dim3(16, 2, 8), 256, 0, stream>>>(l1, xyz1, idxb, l1selT, p1selT);
  transpose_posq_kernel<<<dim3(16, 8, 8), dim3(64, 4), 0, stream>>>(
      l2, xyz2, posw, qinT, l2T);

  // G1: h1 = l1selT·mlp_w1^T + b1  -> bf16 + LN stats
  gemm_u<0, 0, true, false, false, 2><<<dim3(2, 8, 8), 256, 0, stream>>>(
      l1selT, T256, 256, wb_mlp_w1, 0, 256, 0, h1, T256, 256, mlp_b1,
      nullptr, 0, 256, 1.0f, nullptr, nullptr, nullptr, nullptr, 0.f, h1_s1, h1_s2);
  // G2: x2T = relu(LN(h1))·mlp_w2^T + b2  (A transformed)
  gemm_u<1, 0, true, false, false, 1><<<dim3(4, 8, 8), 256, 0, stream>>>(
      h1, T256, 256, wb_mlp_w2, 0, 256, 0, x2T, T512, 512, mlp_b2,
      nullptr, 0, 256, 1.0f, h1_s1, h1_s2, mlp_g1, mlp_be1, 0.f, nullptr, nullptr);

  kin_kernel<<<8192, 128, 0, stream>>>(x2T, p1selT, posw, kinT);

  // Gqk: z 0..7 -> qT = qinT·qw^T ; z 8..15 -> kT = kinT·kw^T
  gemm_u<0, 0, false, false, false, 1><<<dim3(4, 8, 16), 256, 0, stream>>>(
      qinT, T512, 512, wb_qw, 0, 512, 262144, qT, T512, 512, nullptr,
      nullptr, 0, 512, 1.0f, nullptr, nullptr, nullptr, nullptr, 0.f, nullptr, nullptr);
  // Gv: v[c][m] = vw·x2T^T
  gemm_u<0, 0, false, false, false, 1><<<dim3(8, 4, 8), 256, 0, stream>>>(
      wb_vw, 0, 512, x2T, T512, 512, 0, vbf, T512, 1024, nullptr,
      nullptr, 0, 512, 1.0f, nullptr, nullptr, nullptr, nullptr, 0.f, nullptr, nullptr);

  // G7: p = exp(qT·kT^T/scale) -> bf16 + rowsum
  gemm_u<0, 0, false, false, false, 3><<<dim3(8, 8, 8), 256, 0, stream>>>(
      qT, T512, 512, kT, T512, 512, 0, pbuf, T1024, 1024, nullptr,
      nullptr, 0, 512, inv_scale, nullptr, nullptr, nullptr, nullptr, 0.f, rowsum, nullptr);
  // G8: o = (p·v^T)/rowsum + l2T -> bf16 + LN stats
  gemm_u<0, 0, false, false, true, 4><<<dim3(4, 8, 8), 256, 0, stream>>>(
      pbuf, T1024, 1024, vbf, T512, 1024, 0, obuf, T512, 512, nullptr,
      l2T, T512, 1024, 1.0f, rowsum, nullptr, nullptr, nullptr, 0.f, o_s1, o_s2);
  // G9: g1 = leaky(LN(o))·m1_w1^T + b1 -> bf16 + LN stats (A transformed)
  gemm_u<1, 0, true, false, false, 2><<<dim3(4, 8, 8), 256, 0, stream>>>(
      obuf, T512, 512, wb_m1w1, 0, 512, 0, g1buf, T512, 512, m1_b1,
      nullptr, 0, 512, 1.0f, o_s1, o_s2, norm_g, norm_b, 0.01f, g1_s1, g1_s2);
  // G10: out[r][n] = m1_w2·relu(LN(g1))^T + b2 -> f32 d_out (B transformed)
  gemm_u<0, 1, false, true, false, 0><<<dim3(8, 2, 8), 256, 0, stream>>>(
      wb_m1w2, 0, 512, g1buf, T512, 512, 0, outp, 256L * 1024, 1024, m1_b2,
      nullptr, 0, 512, 1.0f, g1_s1, g1_s2, m1_g, m1_be, 0.f, nullptr, nullptr);
}

// Round 6
// 356.130 us; speedup vs baseline: 1.0444x; 1.0444x over previous
//
#include <hip/hip_runtime.h>
#include <math.h>

// ---------------------------------------------------------------------------
// (B, Cin, Cout, Rout, N1, N2) = (8, 256, 512, 256, 4096, 1024)
// Activations token-major X[b][n][c] (c contiguous) except v [c][m].
// LN/softmax fused into GEMM epilogues (stats) / staging (apply).
// ---------------------------------------------------------------------------

typedef __attribute__((ext_vector_type(8))) short short8x;
typedef __attribute__((ext_vector_type(4))) float f32x4;

__device__ __forceinline__ unsigned short f2b(float f) {
  unsigned int u = __float_as_uint(f);
  unsigned int r = u + 0x7FFFu + ((u >> 16) & 1u);
  return (unsigned short)(r >> 16);
}
__device__ __forceinline__ float b2f(unsigned short h) {
  return __uint_as_float(((unsigned int)h) << 16);
}

__device__ __forceinline__ void cp16(const unsigned short* g, unsigned short* l) {
  __builtin_amdgcn_global_load_lds(
      (const __attribute__((address_space(1))) void*)g,
      (__attribute__((address_space(3))) void*)l, 16, 0, 0);
}

// ===========================================================================
// prep: y=0..6 weight f32->bf16; y=7 transpose l2 + pos_q (+l2T copy);
//       y=8 selA: q1v[b][o] = sum_c q1w[o,c]*l1[b,c,0]
// ===========================================================================
__global__ void __launch_bounds__(256) prep_kernel(
    const float* w0, const float* w1, const float* w2, const float* w3,
    const float* w4, const float* w5, const float* w6,
    unsigned short* d0, unsigned short* d1, unsigned short* d2,
    unsigned short* d3, unsigned short* d4, unsigned short* d5,
    unsigned short* d6,
    const float* __restrict__ l1, const float* __restrict__ q1w,
    float* __restrict__ q1v,
    const float* __restrict__ l2, const float* __restrict__ xyz2,
    const float* __restrict__ posw, unsigned short* __restrict__ qinT,
    float* __restrict__ l2T) {
  __shared__ float tile[64][65];
  __shared__ float sx[3][64];
  __shared__ float col[256];
  const int t = threadIdx.x;
  const int y = blockIdx.y;

  if (y == 7) {  // transpose + pos_q
    if (blockIdx.x >= 1024) return;
    const int b = blockIdx.x >> 7;
    const int rem = blockIdx.x & 127;
    const int n0 = (rem & 15) * 64, c0 = (rem >> 4) * 64;
    const int tx = t & 63, ty = t >> 6;
    const float* l2b = l2 + (long)b * 512 * 1024;
    for (int r = 0; r < 16; ++r) {
      const int c = ty * 16 + r;
      tile[c][tx] = l2b[(long)(c0 + c) * 1024 + n0 + tx];
    }
    if (ty < 3) sx[ty][tx] = xyz2[((long)b * 3 + ty) * 1024 + n0 + tx];
    __syncthreads();
    const int c = c0 + tx;
    const float p0 = posw[c * 3], p1 = posw[c * 3 + 1], p2 = posw[c * 3 + 2];
    for (int r = 0; r < 16; ++r) {
      const int nl = ty * 16 + r;
      const float val = tile[tx][nl];
      const long o = ((long)b * 1024 + n0 + nl) * 512 + c;
      l2T[o] = val;
      qinT[o] = f2b(val + p0 * sx[0][nl] + p1 * sx[1][nl] + p2 * sx[2][nl]);
    }
    return;
  }
  if (y == 8) {  // selA
    if (blockIdx.x >= 64) return;
    const int b = blockIdx.x >> 3;
    const int chunk = blockIdx.x & 7;
    col[t] = l1[(long)b * 256 * 4096 + (long)t * 4096];
    __syncthreads();
    const int lane = t & 63, wid = t >> 6;
    const float4 cv = *(const float4*)&col[lane * 4];
    const int obase = chunk * 64 + wid * 16;
#pragma unroll
    for (int oo = 0; oo < 16; ++oo) {
      const int o = obase + oo;
      const float4 wv = ((const float4*)(q1w + (long)o * 256))[lane];
      float s = wv.x * cv.x + wv.y * cv.y + wv.z * cv.z + wv.w * cv.w;
      s += __shfl_xor(s, 1); s += __shfl_xor(s, 2); s += __shfl_xor(s, 4);
      s += __shfl_xor(s, 8); s += __shfl_xor(s, 16); s += __shfl_xor(s, 32);
      if (lane == 0) q1v[b * 512 + o] = s;
    }
    return;
  }
  // weight conversion
  const float* src;
  unsigned short* dst;
  int n;
  switch (y) {
    case 0: src = w0; dst = d0; n = 65536; break;
    case 1: src = w1; dst = d1; n = 131072; break;
    case 2: src = w2; dst = d2; n = 262144; break;
    case 3: src = w3; dst = d3; n = 262144; break;
    case 4: src = w4; dst = d4; n = 262144; break;
    case 5: src = w5; dst = d5; n = 262144; break;
    default: src = w6; dst = d6; n = 131072; break;
  }
  const int i = (blockIdx.x * 256 + t) * 4;
  if (i < n) {
    const float4 v = *(const float4*)(src + i);
    ushort4 o;
    o.x = f2b(v.x); o.y = f2b(v.y); o.z = f2b(v.z); o.w = f2b(v.w);
    *(ushort4*)(dst + i) = o;
  }
}

// ===========================================================================
// selB: wvec[b][c] += sum_{o in chunk} k1w[o][c] * q1v[b][o]   (wvec zeroed)
// ===========================================================================
__global__ void __launch_bounds__(256) selB_kernel(
    const float* __restrict__ k1w, const float* __restrict__ q1v,
    float* __restrict__ wvec) {
  const int b = blockIdx.x;
  const int chunk = blockIdx.y;
  __shared__ float qs[64];
  const int t = threadIdx.x;
  if (t < 64) qs[t] = q1v[b * 512 + chunk * 64 + t];
  __syncthreads();
  float s = 0.f;
  const float* kp = k1w + (long)(chunk * 64) * 256 + t;
#pragma unroll 8
  for (int oo = 0; oo < 64; ++oo) s += kp[(long)oo * 256] * qs[oo];
  atomicAdd(&wvec[b * 256 + t], s);
}

// ===========================================================================
// scores[b,m] = sum_c wvec[b,c] * l1[b,c,m]   (f32 exact)
// ===========================================================================
__global__ void __launch_bounds__(256) sel_scores_kernel(
    const float* __restrict__ l1, const float* __restrict__ wvec,
    float* __restrict__ scores) {
  const int b = blockIdx.y;
  const int m = blockIdx.x * 256 + threadIdx.x;
  __shared__ float w[256];
  w[threadIdx.x] = wvec[b * 256 + threadIdx.x];
  __syncthreads();
  const float* base = l1 + (long)b * 256 * 4096 + m;
  float s = 0.f;
  for (int c = 0; c < 256; ++c) s += w[c] * base[(long)c * 4096];
  scores[b * 4096 + m] = s;
}

// ===========================================================================
// Exact top-1024 SET per batch (radix select), output index-sorted ascending.
// ===========================================================================
__global__ void __launch_bounds__(256) topk_select_kernel(
    const float* __restrict__ scores, int* __restrict__ idx_out) {
  const int b = blockIdx.x;
  const int t = threadIdx.x;
  __shared__ unsigned int keys[4096];
  __shared__ unsigned int hist[256];
  __shared__ unsigned int sc_prefix, sc_krem;
  __shared__ int s_bin;
  __shared__ unsigned int partial_gt[256], partial_eq[256];

  for (int m = t; m < 4096; m += 256) {
    unsigned int u = __float_as_uint(scores[b * 4096 + m]);
    u ^= (u & 0x80000000u) ? 0xFFFFFFFFu : 0x80000000u;
    keys[m] = u;
  }
  if (t == 0) { sc_prefix = 0u; sc_krem = 1024u; }
  __syncthreads();

  unsigned int prefmask = 0u;
  for (int shift = 24; shift >= 0; shift -= 8) {
    hist[t] = 0u;
    if (t == 0) s_bin = 0;
    __syncthreads();
    const unsigned int prefix = sc_prefix;
    for (int m = t; m < 4096; m += 256) {
      unsigned int key = keys[m];
      if ((key & prefmask) == prefix) atomicAdd(&hist[(key >> shift) & 255u], 1u);
    }
    __syncthreads();
    for (int off = 1; off < 256; off <<= 1) {
      unsigned int v = hist[t] + ((t + off < 256) ? hist[t + off] : 0u);
      __syncthreads();
      hist[t] = v;
      __syncthreads();
    }
    const unsigned int krem = sc_krem;
    if (hist[t] >= krem) atomicMax(&s_bin, t);
    __syncthreads();
    if (t == 0) {
      const int bin = s_bin;
      sc_krem = krem - ((bin < 255) ? hist[bin + 1] : 0u);
      sc_prefix = prefix | ((unsigned int)bin << shift);
    }
    prefmask |= (0xFFu << shift);
    __syncthreads();
  }
  const unsigned int cutoff = sc_prefix;
  const unsigned int need = sc_krem;

  unsigned int gt = 0u, eq = 0u;
  const int base = t * 16;
  for (int i = 0; i < 16; ++i) {
    unsigned int key = keys[base + i];
    gt += (key > cutoff);
    eq += (key == cutoff);
  }
  partial_gt[t] = gt;
  partial_eq[t] = eq;
  __syncthreads();
  for (int off = 1; off < 256; off <<= 1) {
    unsigned int g = partial_gt[t] + ((t >= off) ? partial_gt[t - off] : 0u);
    unsigned int e2 = partial_eq[t] + ((t >= off) ? partial_eq[t - off] : 0u);
    __syncthreads();
    partial_gt[t] = g;
    partial_eq[t] = e2;
    __syncthreads();
  }
  const unsigned int pref_gt = partial_gt[t] - gt;
  const unsigned int pref_eq = partial_eq[t] - eq;
  unsigned int pos = pref_gt + ((pref_eq < need) ? pref_eq : need);
  unsigned int eqr = pref_eq;
  for (int i = 0; i < 16; ++i) {
    unsigned int key = keys[base + i];
    bool sel = (key > cutoff);
    if (key == cutoff) sel = sel || (eqr++ < need);
    if (sel) idx_out[b * 1024 + (pos++)] = base + i;
  }
}

// ===========================================================================
// Gather (idx ascending): l1selT[b][j][c] bf16 token-major, p1selT f32.
// ===========================================================================
__global__ void __launch_bounds__(256) gather_sel_kernel(
    const float* __restrict__ l1, const float* __restrict__ xyz1,
    const int* __restrict__ idx, unsigned short* __restrict__ l1selT,
    float* __restrict__ p1selT) {
  const int b = blockIdx.z;
  const int j = blockIdx.x * 64 + (threadIdx.x & 63);
  const int cz = blockIdx.y;
  const int cg = threadIdx.x >> 6;
  const int ix = idx[b * 1024 + j];
  const float* src = l1 + (long)b * 256 * 4096 + ix;
  unsigned short* dst = l1selT + ((long)b * 1024 + j) * 256;
#pragma unroll
  for (int it = 0; it < 8; ++it) {
    const int c = cz * 128 + it * 16 + cg * 4;
    const float x0 = src[(long)(c + 0) * 4096];
    const float x1 = src[(long)(c + 1) * 4096];
    const float x2 = src[(long)(c + 2) * 4096];
    const float x3 = src[(long)(c + 3) * 4096];
    ushort4 o;
    o.x = f2b(x0); o.y = f2b(x1); o.z = f2b(x2); o.w = f2b(x3);
    *(ushort4*)&dst[c] = o;
  }
  if (cz == 0 && cg == 0) {
    float* dp = p1selT + ((long)b * 1024 + j) * 3;
#pragma unroll
    for (int d = 0; d < 3; ++d) dp[d] = xyz1[((long)b * 3 + d) * 4096 + ix];
  }
}

// ===========================================================================
// Unified MFMA bf16 GEMM.  D = alpha*A[M][K]·Bt[N][K]^T (+bias)(+res)
// 128x128 tile, 4 waves, BK=32 double-buffered, cp16 staging, XOR swizzle.
// TRA/TRB: operand LN(+act)-transformed while staging.
// EPI: 0 f32 out | 1 bf16 out | 2 bf16 + row LN-stats | 3 exp + rowsum
//    | 4 bf16, acc/ts1[row] (+res), + LN-stats | 5 bf16 + kin second output
// ===========================================================================
template <int TRA, int TRB, bool BCOL, bool BROW, bool RES, int EPI>
__global__ void __launch_bounds__(256) gemm_u(
    const unsigned short* __restrict__ A, long sA, int ldA,
    const unsigned short* __restrict__ Bt, long sB, int ldB, long sB8,
    void* __restrict__ Yv, long sY, int ldY,
    const float* __restrict__ bias,
    const float* __restrict__ res, long sR,
    int K, float alpha,
    const float* __restrict__ ts1, const float* __restrict__ ts2,
    const float* __restrict__ tg, const float* __restrict__ tb, float tslope,
    float* __restrict__ os1, float* __restrict__ os2,
    const float* __restrict__ kpos, const float* __restrict__ kpw,
    unsigned short* __restrict__ Y2) {
  __shared__ __align__(16) unsigned short ldsA[2][128 * 32];
  __shared__ __align__(16) unsigned short ldsB[2][128 * 32];
  const int tid = threadIdx.x;
  const int lane = tid & 63;
  const int wv = tid >> 6;
  const int wm = wv >> 1, wn = wv & 1;
  const int n0 = blockIdx.x * 128, m0 = blockIdx.y * 128, b = blockIdx.z;
  A += (long)b * sA;
  Bt += (long)(b & 7) * sB + (long)(b >> 3) * sB8;
  const int lane15 = lane & 15, q = lane >> 4;

  const int srow0 = wv * 32 + (lane >> 2);
  const int srow1 = srow0 + 16;
  const int ks0 = ((lane & 3) ^ ((srow0 >> 1) & 3)) << 3;
  const int ks1 = ((lane & 3) ^ ((srow1 >> 1) & 3)) << 3;
  const unsigned short* gA0 = A + (long)(m0 + srow0) * ldA + ks0;
  const unsigned short* gA1 = A + (long)(m0 + srow1) * ldA + ks1;
  const unsigned short* gB0 = Bt + (long)(n0 + srow0) * ldB + ks0;
  const unsigned short* gB1 = Bt + (long)(n0 + srow1) * ldB + ks1;
  unsigned short* lA0[2] = {&ldsA[0][(wv * 32) * 32], &ldsA[1][(wv * 32) * 32]};
  unsigned short* lA1[2] = {&ldsA[0][(wv * 32 + 16) * 32], &ldsA[1][(wv * 32 + 16) * 32]};
  unsigned short* lB0[2] = {&ldsB[0][(wv * 32) * 32], &ldsB[1][(wv * 32) * 32]};
  unsigned short* lB1[2] = {&ldsB[0][(wv * 32 + 16) * 32], &ldsB[1][(wv * 32 + 16) * 32]};

  constexpr bool TR = (TRA + TRB) != 0;
  const int trow = tid & 127, thalf = tid >> 7;
  float t_mu = 0.f, t_rs = 0.f;
  const unsigned short* tsrc = nullptr;
  int toff0 = 0, toff1 = 0;
  if constexpr (TR) {
    const int row0 = (TRA ? m0 : n0) + trow;
    const int ridx = (b & 7) * 1024 + row0;
    const float Cf = (float)K;
    const float s1v = ts1[ridx], s2v = ts2[ridx];
    t_mu = s1v / Cf;
    t_rs = rsqrtf(s2v / Cf - t_mu * t_mu + 1e-5f);
    tsrc = (TRA ? A + (long)row0 * ldA : Bt + (long)row0 * ldB) + thalf * 16;
    const int sw = (trow >> 1) & 3;
    toff0 = trow * 32 + ((((thalf * 2) ^ sw)) << 3);
    toff1 = trow * 32 + ((((thalf * 2 + 1) ^ sw)) << 3);
  }

  auto t_apply = [&](int kk, short8x r0, short8x r1, int buf) {
    union { short8x v; unsigned short u[8]; } a0, a1, w0, w1;
    a0.v = r0; a1.v = r1;
    const float4* gp = (const float4*)(tg + kk + thalf * 16);
    const float4* bp = (const float4*)(tb + kk + thalf * 16);
    const float4 g0 = gp[0], g1 = gp[1], g2 = gp[2], g3 = gp[3];
    const float4 e0 = bp[0], e1 = bp[1], e2 = bp[2], e3 = bp[3];
    const float gg[16] = {g0.x, g0.y, g0.z, g0.w, g1.x, g1.y, g1.z, g1.w,
                          g2.x, g2.y, g2.z, g2.w, g3.x, g3.y, g3.z, g3.w};
    const float ee[16] = {e0.x, e0.y, e0.z, e0.w, e1.x, e1.y, e1.z, e1.w,
                          e2.x, e2.y, e2.z, e2.w, e3.x, e3.y, e3.z, e3.w};
#pragma unroll
    for (int c = 0; c < 8; ++c) {
      float y = (b2f(a0.u[c]) - t_mu) * t_rs * gg[c] + ee[c];
      y = y > 0.f ? y : tslope * y;
      w0.u[c] = f2b(y);
    }
#pragma unroll
    for (int c = 0; c < 8; ++c) {
      float y = (b2f(a1.u[c]) - t_mu) * t_rs * gg[8 + c] + ee[8 + c];
      y = y > 0.f ? y : tslope * y;
      w1.u[c] = f2b(y);
    }
    unsigned short* base = TRA ? &ldsA[buf][0] : &ldsB[buf][0];
    *(short8x*)&base[toff0] = w0.v;
    *(short8x*)&base[toff1] = w1.v;
  };

  short8x tr0, tr1;
  if constexpr (TR) {
    tr0 = *(const short8x*)(tsrc + 0);
    tr1 = *(const short8x*)(tsrc + 8);
  }
  if constexpr (!TRA) { cp16(gA0, lA0[0]); cp16(gA1, lA1[0]); }
  if constexpr (!TRB) { cp16(gB0, lB0[0]); cp16(gB1, lB1[0]); }
  if constexpr (TR) t_apply(0, tr0, tr1, 0);

  f32x4 acc[4][4] = {};
  int cur = 0;
  for (int k0 = 0; k0 < K; k0 += 32) {
    __syncthreads();
    const bool nxt = (k0 + 32 < K);
    if (nxt) {
      const int nk = k0 + 32;
      if constexpr (!TRA) { cp16(gA0 + nk, lA0[cur ^ 1]); cp16(gA1 + nk, lA1[cur ^ 1]); }
      if constexpr (!TRB) { cp16(gB0 + nk, lB0[cur ^ 1]); cp16(gB1 + nk, lB1[cur ^ 1]); }
      if constexpr (TR) {
        tr0 = *(const short8x*)(tsrc + nk);
        tr1 = *(const short8x*)(tsrc + nk + 8);
      }
    }
    short8x af[4], bfr[4];
#pragma unroll
    for (int i = 0; i < 4; ++i) {
      const int m = wm * 64 + i * 16 + lane15;
      af[i] = *(const short8x*)&ldsA[cur][m * 32 + ((q ^ ((m >> 1) & 3)) << 3)];
      const int n = wn * 64 + i * 16 + lane15;
      bfr[i] = *(const short8x*)&ldsB[cur][n * 32 + ((q ^ ((n >> 1) & 3)) << 3)];
    }
#pragma unroll
    for (int i = 0; i < 4; ++i)
#pragma unroll
      for (int j = 0; j < 4; ++j)
        acc[i][j] = __builtin_amdgcn_mfma_f32_16x16x32_bf16(af[i], bfr[j], acc[i][j], 0, 0, 0);
    if (nxt) {
      if constexpr (TR) t_apply(k0 + 32, tr0, tr1, cur ^ 1);
    }
    cur ^= 1;
  }

  // epilogue
  float* Yf = (float*)Yv;
  unsigned short* Yh = (unsigned short*)Yv;
  if constexpr (EPI == 0) Yf += (long)b * sY; else Yh += (long)b * sY;
  if constexpr (EPI == 5) Y2 += (long)b * sY;
  if constexpr (RES) res += (long)b * sR;
  float inv_[4];
  float kq0[4], kq1[4], kq2[4];
  float ssum[4][4], ssq[4][4];
#pragma unroll
  for (int i = 0; i < 4; ++i)
#pragma unroll
    for (int r = 0; r < 4; ++r) { ssum[i][r] = 0.f; ssq[i][r] = 0.f; }

#pragma unroll
  for (int i = 0; i < 4; ++i) {
    if constexpr (EPI == 4) {
#pragma unroll
      for (int r = 0; r < 4; ++r)
        inv_[r] = 1.f / ts1[(b & 7) * 1024 + m0 + wm * 64 + i * 16 + q * 4 + r];
    }
    if constexpr (EPI == 5) {
#pragma unroll
      for (int r = 0; r < 4; ++r) {
        const int m_g = m0 + wm * 64 + i * 16 + q * 4 + r;
        const float* pp = kpos + ((long)b * 1024 + m_g) * 3;
        kq0[r] = pp[0]; kq1[r] = pp[1]; kq2[r] = pp[2];
      }
    }
#pragma unroll
    for (int j = 0; j < 4; ++j) {
      const int n_g = n0 + wn * 64 + j * 16 + lane15;
      const float bc = BCOL ? bias[n_g] : 0.f;
      float pw0 = 0.f, pw1 = 0.f, pw2 = 0.f;
      if constexpr (EPI == 5) {
        pw0 = kpw[n_g * 3]; pw1 = kpw[n_g * 3 + 1]; pw2 = kpw[n_g * 3 + 2];
      }
#pragma unroll
      for (int r = 0; r < 4; ++r) {
        const int m_g = m0 + wm * 64 + i * 16 + q * 4 + r;
        float y = acc[i][j][r] * alpha;
        if constexpr (EPI == 4) y *= inv_[r];
        if constexpr (BCOL) y += bc;
        if constexpr (BROW) y += bias[m_g];
        if constexpr (RES) y += res[(long)m_g * ldY + n_g];
        if constexpr (EPI == 3) y = __expf(y);
        const long off = (long)m_g * ldY + n_g;
        if constexpr (EPI == 0) Yf[off] = y;
        else Yh[off] = f2b(y);
        if constexpr (EPI == 5)
          Y2[off] = f2b(y + pw0 * kq0[r] + pw1 * kq1[r] + pw2 * kq2[r]);
        if constexpr (EPI == 2 || EPI == 3 || EPI == 4) {
          ssum[i][r] += y; ssq[i][r] += y * y;
        }
      }
    }
  }
  if constexpr (EPI == 2 || EPI == 4) {
#pragma unroll
    for (int i = 0; i < 4; ++i)
#pragma unroll
      for (int r = 0; r < 4; ++r) {
        float s = ssum[i][r], q2 = ssq[i][r];
        s += __shfl_xor(s, 1); q2 += __shfl_xor(q2, 1);
        s += __shfl_xor(s, 2); q2 += __shfl_xor(q2, 2);
        s += __shfl_xor(s, 4); q2 += __shfl_xor(q2, 4);
        s += __shfl_xor(s, 8); q2 += __shfl_xor(q2, 8);
        if (lane15 == 0) {
          const int ridx = (b & 7) * 1024 + m0 + wm * 64 + i * 16 + q * 4 + r;
          atomicAdd(&os1[ridx], s);
          atomicAdd(&os2[ridx], q2);
        }
      }
  } else if constexpr (EPI == 3) {
#pragma unroll
    for (int i = 0; i < 4; ++i)
#pragma unroll
      for (int r = 0; r < 4; ++r) {
        float s = ssum[i][r];
        s += __shfl_xor(s, 1);
        s += __shfl_xor(s, 2);
        s += __shfl_xor(s, 4);
        s += __shfl_xor(s, 8);
        if (lane15 == 0) {
          const int ridx = (b & 7) * 1024 + m0 + wm * 64 + i * 16 + q * 4 + r;
          atomicAdd(&os1[ridx], s);
        }
      }
  }
}

// ===========================================================================
// Launch
// ===========================================================================
extern "C" void kernel_launch(void* const* d_in, const int* in_sizes, int n_in,
                              void* d_out, int out_size, void* d_ws,
                              size_t ws_size, hipStream_t stream) {
  const float* l1 = (const float*)d_in[0];
  const float* xyz1 = (const float*)d_in[1];
  const float* l2 = (const float*)d_in[2];
  const float* xyz2 = (const float*)d_in[3];
  const float* q1w = (const float*)d_in[4];
  const float* k1w = (const float*)d_in[5];
  const float* mlp_w1 = (const float*)d_in[6];
  const float* mlp_b1 = (const float*)d_in[7];
  const float* mlp_g1 = (const float*)d_in[8];
  const float* mlp_be1 = (const float*)d_in[9];
  const float* mlp_w2 = (const float*)d_in[10];
  const float* mlp_b2 = (const float*)d_in[11];
  const float* qw = (const float*)d_in[12];
  const float* kw = (const float*)d_in[13];
  const float* vw = (const float*)d_in[14];
  const float* posw = (const float*)d_in[15];
  const float* norm_g = (const float*)d_in[16];
  const float* norm_b = (const float*)d_in[17];
  const float* m1_w1 = (const float*)d_in[18];
  const float* m1_b1 = (const float*)d_in[19];
  const float* m1_g = (const float*)d_in[20];
  const float* m1_be = (const float*)d_in[21];
  const float* m1_w2 = (const float*)d_in[22];
  const float* m1_b2 = (const float*)d_in[23];

  char* ws = (char*)d_ws;
  const long MiB = 1048576;
  unsigned short* wb_mlp_w1 = (unsigned short*)(ws + 0);
  unsigned short* wb_mlp_w2 = (unsigned short*)(ws + 131072);
  unsigned short* wb_qw = (unsigned short*)(ws + 393216);
  unsigned short* wb_kw = (unsigned short*)(ws + 917504);
  unsigned short* wb_vw = (unsigned short*)(ws + 1441792);
  unsigned short* wb_m1w1 = (unsigned short*)(ws + 1966080);
  unsigned short* wb_m1w2 = (unsigned short*)(ws + 2490368);
  float* scores = (float*)(ws + 2752512);   // 128 KB
  int* idxb = (int*)(ws + 2891776);         // 32 KB
  float* p1selT = (float*)(ws + 2924544);   // 96 KB -> ends 3022848
  float* q1v = (float*)(ws + 3022848);      // 16 KB
  // zeroed region [3399680, 3637248): wvec (8 KB) + stats (7 x 32 KB)
  float* wvec = (float*)(ws + 3399680);
  float* rowsum = (float*)(ws + 3407872);
  float* h1_s1 = (float*)(ws + 3440640);
  float* h1_s2 = (float*)(ws + 3473408);
  float* o_s1 = (float*)(ws + 3506176);
  float* o_s2 = (float*)(ws + 3538944);
  float* g1_s1 = (float*)(ws + 3571712);
  float* g1_s2 = (float*)(ws + 3604480);
  // big buffers
  unsigned short* l1selT = (unsigned short*)(ws + 4 * MiB);   // [4,8)
  unsigned short* h1 = (unsigned short*)(ws + 8 * MiB);       // [8,12)
  unsigned short* x2T = (unsigned short*)(ws + 12 * MiB);     // [12,20)
  unsigned short* qinT = (unsigned short*)(ws + 20 * MiB);    // [20,28)
  unsigned short* kinT = (unsigned short*)(ws + 28 * MiB);    // [28,36) contiguous
  float* l2T = (float*)(ws + 36 * MiB);                       // [36,52) f32
  unsigned short* qT = (unsigned short*)(ws + 52 * MiB);      // [52,60)
  unsigned short* kT = (unsigned short*)(ws + 60 * MiB);      // [60,68) contiguous
  unsigned short* vbf = (unsigned short*)(ws + 68 * MiB);     // [68,76)
  unsigned short* pbuf = (unsigned short*)(ws + 76 * MiB);    // [76,92)
  unsigned short* obuf = (unsigned short*)(ws + 92 * MiB);    // [92,100)
  unsigned short* g1buf = (unsigned short*)(ws + 100 * MiB);  // [100,108)
  float* outp = (float*)d_out;

  const float inv_scale = 1.0f / sqrtf(512.0f);
  const long T256 = 1024L * 256, T512 = 1024L * 512, T1024 = 1024L * 1024;

  hipMemsetAsync(ws + 3399680, 0, 237568, stream);

  prep_kernel<<<dim3(1024, 9), 256, 0, stream>>>(
      mlp_w1, mlp_w2, qw, kw, vw, m1_w1, m1_w2,
      wb_mlp_w1, wb_mlp_w2, wb_qw, wb_kw, wb_vw, wb_m1w1, wb_m1w2,
      l1, q1w, q1v, l2, xyz2, posw, qinT, l2T);
  selB_kernel<<<dim3(8, 8), 256, 0, stream>>>(k1w, q1v, wvec);
  sel_scores_kernel<<<dim3(16, 8), 256, 0, stream>>>(l1, wvec, scores);
  topk_select_kernel<<<8, 256, 0, stream>>>(scores, idxb);
  gather_sel_kernel<<<dim3(16, 2, 8), 256, 0, stream>>>(l1, xyz1, idxb, l1selT, p1selT);

  // G1: h1 = l1selT·mlp_w1^T + b1 -> bf16 + LN stats
  gemm_u<0, 0, true, false, false, 2><<<dim3(2, 8, 8), 256, 0, stream>>>(
      l1selT, T256, 256, wb_mlp_w1, 0, 256, 0, h1, T256, 256, mlp_b1,
      nullptr, 0, 256, 1.0f, nullptr, nullptr, nullptr, nullptr, 0.f,
      h1_s1, h1_s2, nullptr, nullptr, nullptr);
  // G2: x2T = relu(LN(h1))·mlp_w2^T + b2; also kinT = x2 + posw·p1sel (EPI 5)
  gemm_u<1, 0, true, false, false, 5><<<dim3(4, 8, 8), 256, 0, stream>>>(
      h1, T256, 256, wb_mlp_w2, 0, 256, 0, x2T, T512, 512, mlp_b2,
      nullptr, 0, 256, 1.0f, h1_s1, h1_s2, mlp_g1, mlp_be1, 0.f,
      nullptr, nullptr, p1selT, posw, kinT);

  // Gqk: z 0..7 -> qT = qinT·qw^T ; z 8..15 -> kT = kinT·kw^T
  gemm_u<0, 0, false, false, false, 1><<<dim3(4, 8, 16), 256, 0, stream>>>(
      qinT, T512, 512, wb_qw, 0, 512, 262144, qT, T512, 512, nullptr,
      nullptr, 0, 512, 1.0f, nullptr, nullptr, nullptr, nullptr, 0.f,
      nullptr, nullptr, nullptr, nullptr, nullptr);
  // Gv: v[c][m] = vw·x2T^T
  gemm_u<0, 0, false, false, false, 1><<<dim3(8, 4, 8), 256, 0, stream>>>(
      wb_vw, 0, 512, x2T, T512, 512, 0, vbf, T512, 1024, nullptr,
      nullptr, 0, 512, 1.0f, nullptr, nullptr, nullptr, nullptr, 0.f,
      nullptr, nullptr, nullptr, nullptr, nullptr);

  // G7: p = exp(qT·kT^T/scale) -> bf16 + rowsum
  gemm_u<0, 0, false, false, false, 3><<<dim3(8, 8, 8), 256, 0, stream>>>(
      qT, T512, 512, kT, T512, 512, 0, pbuf, T1024, 1024, nullptr,
      nullptr, 0, 512, inv_scale, nullptr, nullptr, nullptr, nullptr, 0.f,
      rowsum, nullptr, nullptr, nullptr, nullptr);
  // G8: o = (p·v^T)/rowsum + l2T -> bf16 + LN stats
  gemm_u<0, 0, false, false, true, 4><<<dim3(4, 8, 8), 256, 0, stream>>>(
      pbuf, T1024, 1024, vbf, T512, 1024, 0, obuf, T512, 512, nullptr,
      l2T, T512, 1024, 1.0f, rowsum, nullptr, nullptr, nullptr, 0.f,
      o_s1, o_s2, nullptr, nullptr, nullptr);
  // G9: g1 = leaky(LN(o))·m1_w1^T + b1 -> bf16 + LN stats (A transformed)
  gemm_u<1, 0, true, false, false, 2><<<dim3(4, 8, 8), 256, 0, stream>>>(
      obuf, T512, 512, wb_m1w1, 0, 512, 0, g1buf, T512, 512, m1_b1,
      nullptr, 0, 512, 1.0f, o_s1, o_s2, norm_g, norm_b, 0.01f,
      g1_s1, g1_s2, nullptr, nullptr, nullptr);
  // G10: out = m1_w2·relu(LN(g1))^T + b2 -> f32 d_out (B transformed)
  gemm_u<0, 1, false, true, false, 0><<<dim3(8, 2, 8), 256, 0, stream>>>(
      wb_m1w2, 0, 512, g1buf, T512, 512, 0, outp, 256L * 1024, 1024, m1_b2,
      nullptr, 0, 512, 1.0f, g1_s1, g1_s2, m1_g, m1_be, 0.f,
      nullptr, nullptr, nullptr, nullptr, nullptr);
}

// Round 8
// 349.072 us; speedup vs baseline: 1.0655x; 1.0202x over previous
//
#include <hip/hip_runtime.h>
#include <math.h>

// ---------------------------------------------------------------------------
// (B, Cin, Cout, Rout, N1, N2) = (8, 256, 512, 256, 4096, 1024)
// Activations token-major X[b][n][c] (c contiguous) except v [c][m].
// LN/softmax fused into GEMM epilogues (stats) / staging (apply).
// R8: 128x64 GEMM tile (BN=64) -> 2x grid, 2-4 blocks/CU (latency overlap).
// ---------------------------------------------------------------------------

typedef __attribute__((ext_vector_type(8))) short short8x;
typedef __attribute__((ext_vector_type(4))) float f32x4;

__device__ __forceinline__ unsigned short f2b(float f) {
  unsigned int u = __float_as_uint(f);
  unsigned int r = u + 0x7FFFu + ((u >> 16) & 1u);
  return (unsigned short)(r >> 16);
}
__device__ __forceinline__ float b2f(unsigned short h) {
  return __uint_as_float(((unsigned int)h) << 16);
}

__device__ __forceinline__ void cp16(const unsigned short* g, unsigned short* l) {
  __builtin_amdgcn_global_load_lds(
      (const __attribute__((address_space(1))) void*)g,
      (__attribute__((address_space(3))) void*)l, 16, 0, 0);
}

// ===========================================================================
// prep: y=0..6 weight f32->bf16; y=7 transpose l2 + pos_q (+l2T copy);
//       y=8 selA: q1v[b][o] = sum_c q1w[o,c]*l1[b,c,0]
// ===========================================================================
__global__ void __launch_bounds__(256) prep_kernel(
    const float* w0, const float* w1, const float* w2, const float* w3,
    const float* w4, const float* w5, const float* w6,
    unsigned short* d0, unsigned short* d1, unsigned short* d2,
    unsigned short* d3, unsigned short* d4, unsigned short* d5,
    unsigned short* d6,
    const float* __restrict__ l1, const float* __restrict__ q1w,
    float* __restrict__ q1v,
    const float* __restrict__ l2, const float* __restrict__ xyz2,
    const float* __restrict__ posw, unsigned short* __restrict__ qinT,
    float* __restrict__ l2T) {
  __shared__ float tile[64][65];
  __shared__ float sx[3][64];
  __shared__ float col[256];
  const int t = threadIdx.x;
  const int y = blockIdx.y;

  if (y == 7) {  // transpose + pos_q
    if (blockIdx.x >= 1024) return;
    const int b = blockIdx.x >> 7;
    const int rem = blockIdx.x & 127;
    const int n0 = (rem & 15) * 64, c0 = (rem >> 4) * 64;
    const int tx = t & 63, ty = t >> 6;
    const float* l2b = l2 + (long)b * 512 * 1024;
    for (int r = 0; r < 16; ++r) {
      const int c = ty * 16 + r;
      tile[c][tx] = l2b[(long)(c0 + c) * 1024 + n0 + tx];
    }
    if (ty < 3) sx[ty][tx] = xyz2[((long)b * 3 + ty) * 1024 + n0 + tx];
    __syncthreads();
    const int c = c0 + tx;
    const float p0 = posw[c * 3], p1 = posw[c * 3 + 1], p2 = posw[c * 3 + 2];
    for (int r = 0; r < 16; ++r) {
      const int nl = ty * 16 + r;
      const float val = tile[tx][nl];
      const long o = ((long)b * 1024 + n0 + nl) * 512 + c;
      l2T[o] = val;
      qinT[o] = f2b(val + p0 * sx[0][nl] + p1 * sx[1][nl] + p2 * sx[2][nl]);
    }
    return;
  }
  if (y == 8) {  // selA
    if (blockIdx.x >= 64) return;
    const int b = blockIdx.x >> 3;
    const int chunk = blockIdx.x & 7;
    col[t] = l1[(long)b * 256 * 4096 + (long)t * 4096];
    __syncthreads();
    const int lane = t & 63, wid = t >> 6;
    const float4 cv = *(const float4*)&col[lane * 4];
    const int obase = chunk * 64 + wid * 16;
#pragma unroll
    for (int oo = 0; oo < 16; ++oo) {
      const int o = obase + oo;
      const float4 wv = ((const float4*)(q1w + (long)o * 256))[lane];
      float s = wv.x * cv.x + wv.y * cv.y + wv.z * cv.z + wv.w * cv.w;
      s += __shfl_xor(s, 1); s += __shfl_xor(s, 2); s += __shfl_xor(s, 4);
      s += __shfl_xor(s, 8); s += __shfl_xor(s, 16); s += __shfl_xor(s, 32);
      if (lane == 0) q1v[b * 512 + o] = s;
    }
    return;
  }
  // weight conversion
  const float* src;
  unsigned short* dst;
  int n;
  switch (y) {
    case 0: src = w0; dst = d0; n = 65536; break;
    case 1: src = w1; dst = d1; n = 131072; break;
    case 2: src = w2; dst = d2; n = 262144; break;
    case 3: src = w3; dst = d3; n = 262144; break;
    case 4: src = w4; dst = d4; n = 262144; break;
    case 5: src = w5; dst = d5; n = 262144; break;
    default: src = w6; dst = d6; n = 131072; break;
  }
  const int i = (blockIdx.x * 256 + t) * 4;
  if (i < n) {
    const float4 v = *(const float4*)(src + i);
    ushort4 o;
    o.x = f2b(v.x); o.y = f2b(v.y); o.z = f2b(v.z); o.w = f2b(v.w);
    *(ushort4*)(dst + i) = o;
  }
}

// ===========================================================================
// selB: wvec[b][c] += sum_{o in chunk} k1w[o][c] * q1v[b][o]   (wvec zeroed)
// ===========================================================================
__global__ void __launch_bounds__(256) selB_kernel(
    const float* __restrict__ k1w, const float* __restrict__ q1v,
    float* __restrict__ wvec) {
  const int b = blockIdx.x;
  const int chunk = blockIdx.y;
  __shared__ float qs[64];
  const int t = threadIdx.x;
  if (t < 64) qs[t] = q1v[b * 512 + chunk * 64 + t];
  __syncthreads();
  float s = 0.f;
  const float* kp = k1w + (long)(chunk * 64) * 256 + t;
#pragma unroll 8
  for (int oo = 0; oo < 64; ++oo) s += kp[(long)oo * 256] * qs[oo];
  atomicAdd(&wvec[b * 256 + t], s);
}

// ===========================================================================
// scores[b,m] = sum_c wvec[b,c] * l1[b,c,m]   (f32 exact)
// ===========================================================================
__global__ void __launch_bounds__(256) sel_scores_kernel(
    const float* __restrict__ l1, const float* __restrict__ wvec,
    float* __restrict__ scores) {
  const int b = blockIdx.y;
  const int m = blockIdx.x * 256 + threadIdx.x;
  __shared__ float w[256];
  w[threadIdx.x] = wvec[b * 256 + threadIdx.x];
  __syncthreads();
  const float* base = l1 + (long)b * 256 * 4096 + m;
  float s = 0.f;
  for (int c = 0; c < 256; ++c) s += w[c] * base[(long)c * 4096];
  scores[b * 4096 + m] = s;
}

// ===========================================================================
// Exact top-1024 SET per batch (radix select), output index-sorted ascending.
// ===========================================================================
__global__ void __launch_bounds__(256) topk_select_kernel(
    const float* __restrict__ scores, int* __restrict__ idx_out) {
  const int b = blockIdx.x;
  const int t = threadIdx.x;
  __shared__ unsigned int keys[4096];
  __shared__ unsigned int hist[256];
  __shared__ unsigned int sc_prefix, sc_krem;
  __shared__ int s_bin;
  __shared__ unsigned int partial_gt[256], partial_eq[256];

  for (int m = t; m < 4096; m += 256) {
    unsigned int u = __float_as_uint(scores[b * 4096 + m]);
    u ^= (u & 0x80000000u) ? 0xFFFFFFFFu : 0x80000000u;
    keys[m] = u;
  }
  if (t == 0) { sc_prefix = 0u; sc_krem = 1024u; }
  __syncthreads();

  unsigned int prefmask = 0u;
  for (int shift = 24; shift >= 0; shift -= 8) {
    hist[t] = 0u;
    if (t == 0) s_bin = 0;
    __syncthreads();
    const unsigned int prefix = sc_prefix;
    for (int m = t; m < 4096; m += 256) {
      unsigned int key = keys[m];
      if ((key & prefmask) == prefix) atomicAdd(&hist[(key >> shift) & 255u], 1u);
    }
    __syncthreads();
    for (int off = 1; off < 256; off <<= 1) {
      unsigned int v = hist[t] + ((t + off < 256) ? hist[t + off] : 0u);
      __syncthreads();
      hist[t] = v;
      __syncthreads();
    }
    const unsigned int krem = sc_krem;
    if (hist[t] >= krem) atomicMax(&s_bin, t);
    __syncthreads();
    if (t == 0) {
      const int bin = s_bin;
      sc_krem = krem - ((bin < 255) ? hist[bin + 1] : 0u);
      sc_prefix = prefix | ((unsigned int)bin << shift);
    }
    prefmask |= (0xFFu << shift);
    __syncthreads();
  }
  const unsigned int cutoff = sc_prefix;
  const unsigned int need = sc_krem;

  unsigned int gt = 0u, eq = 0u;
  const int base = t * 16;
  for (int i = 0; i < 16; ++i) {
    unsigned int key = keys[base + i];
    gt += (key > cutoff);
    eq += (key == cutoff);
  }
  partial_gt[t] = gt;
  partial_eq[t] = eq;
  __syncthreads();
  for (int off = 1; off < 256; off <<= 1) {
    unsigned int g = partial_gt[t] + ((t >= off) ? partial_gt[t - off] : 0u);
    unsigned int e2 = partial_eq[t] + ((t >= off) ? partial_eq[t - off] : 0u);
    __syncthreads();
    partial_gt[t] = g;
    partial_eq[t] = e2;
    __syncthreads();
  }
  const unsigned int pref_gt = partial_gt[t] - gt;
  const unsigned int pref_eq = partial_eq[t] - eq;
  unsigned int pos = pref_gt + ((pref_eq < need) ? pref_eq : need);
  unsigned int eqr = pref_eq;
  for (int i = 0; i < 16; ++i) {
    unsigned int key = keys[base + i];
    bool sel = (key > cutoff);
    if (key == cutoff) sel = sel || (eqr++ < need);
    if (sel) idx_out[b * 1024 + (pos++)] = base + i;
  }
}

// ===========================================================================
// Gather (idx ascending): l1selT[b][j][c] bf16 token-major, p1selT f32.
// ===========================================================================
__global__ void __launch_bounds__(256) gather_sel_kernel(
    const float* __restrict__ l1, const float* __restrict__ xyz1,
    const int* __restrict__ idx, unsigned short* __restrict__ l1selT,
    float* __restrict__ p1selT) {
  const int b = blockIdx.z;
  const int j = blockIdx.x * 64 + (threadIdx.x & 63);
  const int cz = blockIdx.y;
  const int cg = threadIdx.x >> 6;
  const int ix = idx[b * 1024 + j];
  const float* src = l1 + (long)b * 256 * 4096 + ix;
  unsigned short* dst = l1selT + ((long)b * 1024 + j) * 256;
#pragma unroll
  for (int it = 0; it < 8; ++it) {
    const int c = cz * 128 + it * 16 + cg * 4;
    const float x0 = src[(long)(c + 0) * 4096];
    const float x1 = src[(long)(c + 1) * 4096];
    const float x2 = src[(long)(c + 2) * 4096];
    const float x3 = src[(long)(c + 3) * 4096];
    ushort4 o;
    o.x = f2b(x0); o.y = f2b(x1); o.z = f2b(x2); o.w = f2b(x3);
    *(ushort4*)&dst[c] = o;
  }
  if (cz == 0 && cg == 0) {
    float* dp = p1selT + ((long)b * 1024 + j) * 3;
#pragma unroll
    for (int d = 0; d < 3; ++d) dp[d] = xyz1[((long)b * 3 + d) * 4096 + ix];
  }
}

// ===========================================================================
// Unified MFMA bf16 GEMM, tile 128(M) x BN(N), BK=32 double-buffered.
// D = alpha*A[M][K]·Bt[N][K]^T (+bias)(+res); cp16 staging, XOR swizzle.
// TRA/TRB: operand LN(+act)-transformed while staging.
// EPI: 0 f32 out | 1 bf16 out | 2 bf16 + row LN-stats | 3 exp + rowsum
//    | 4 bf16, acc/ts1[row] (+res), + LN-stats | 5 bf16 + kin second output
// ===========================================================================
template <int BN, int TRA, int TRB, bool BCOL, bool BROW, bool RES, int EPI>
__global__ void __launch_bounds__(256) gemm_u(
    const unsigned short* __restrict__ A, long sA, int ldA,
    const unsigned short* __restrict__ Bt, long sB, int ldB, long sB8,
    void* __restrict__ Yv, long sY, int ldY,
    const float* __restrict__ bias,
    const float* __restrict__ res, long sR,
    int K, float alpha,
    const float* __restrict__ ts1, const float* __restrict__ ts2,
    const float* __restrict__ tg, const float* __restrict__ tb, float tslope,
    float* __restrict__ os1, float* __restrict__ os2,
    const float* __restrict__ kpos, const float* __restrict__ kpw,
    unsigned short* __restrict__ Y2) {
  constexpr int JN = BN / 32;             // 16-wide n-frags per wave (2 or 4)
  __shared__ __align__(16) unsigned short ldsA[2][128 * 32];
  __shared__ __align__(16) unsigned short ldsB[2][BN * 32];
  const int tid = threadIdx.x;
  const int lane = tid & 63;
  const int wv = tid >> 6;
  const int wm = wv >> 1, wn = wv & 1;
  const int n0 = blockIdx.x * BN, m0 = blockIdx.y * 128, b = blockIdx.z;
  A += (long)b * sA;
  Bt += (long)(b & 7) * sB + (long)(b >> 3) * sB8;
  const int lane15 = lane & 15, q = lane >> 4;

  // A staging: 4 waves x 2 cp16 (32 rows each) = 128 rows
  const int srow0 = wv * 32 + (lane >> 2);
  const int srow1 = srow0 + 16;
  const int ks0 = ((lane & 3) ^ ((srow0 >> 1) & 3)) << 3;
  const int ks1 = ((lane & 3) ^ ((srow1 >> 1) & 3)) << 3;
  const unsigned short* gA0 = A + (long)(m0 + srow0) * ldA + ks0;
  const unsigned short* gA1 = A + (long)(m0 + srow1) * ldA + ks1;
  unsigned short* lA0[2] = {&ldsA[0][(wv * 32) * 32], &ldsA[1][(wv * 32) * 32]};
  unsigned short* lA1[2] = {&ldsA[0][(wv * 32 + 16) * 32], &ldsA[1][(wv * 32 + 16) * 32]};
  // B staging: BN=128 -> like A; BN=64 -> 4 waves x 1 cp16 (16 rows each)
  const int srowB = (BN == 128) ? srow0 : (wv * 16 + (lane >> 2));
  const int ksB = ((lane & 3) ^ ((srowB >> 1) & 3)) << 3;
  const unsigned short* gB0 = Bt + (long)(n0 + srowB) * ldB + ksB;
  const unsigned short* gB1 = Bt + (long)(n0 + srow1) * ldB + ks1;  // BN=128 only
  unsigned short* lB0[2] = {&ldsB[0][((BN == 128 ? wv * 32 : wv * 16)) * 32],
                            &ldsB[1][((BN == 128 ? wv * 32 : wv * 16)) * 32]};
  unsigned short* lB1[2] = {&ldsB[0][((wv * 32 + 16) * 32) % (BN * 32)],
                            &ldsB[1][((wv * 32 + 16) * 32) % (BN * 32)]};

  // transform staging (LN while writing LDS)
  constexpr bool TR = (TRA + TRB) != 0;
  constexpr int TROWS = TRA ? 128 : BN;    // rows to transform
  constexpr int TSH = (TROWS == 128) ? 7 : 6;
  constexpr int TCH = (TROWS == 128) ? 2 : 1;  // 8-elem chunks per thread
  const int trow = tid & (TROWS - 1), tpart = tid >> TSH;
  float t_mu = 0.f, t_rs = 0.f;
  const unsigned short* tsrc = nullptr;
  int toff[2] = {0, 0};
  int tkof = 0;
  if constexpr (TR) {
    const int row0 = (TRA ? m0 : n0) + trow;
    const int ridx = (b & 7) * 1024 + row0;
    const float Cf = (float)K;
    const float s1v = ts1[ridx], s2v = ts2[ridx];
    t_mu = s1v / Cf;
    t_rs = rsqrtf(s2v / Cf - t_mu * t_mu + 1e-5f);
    tkof = tpart * (TCH * 8);
    tsrc = (TRA ? A + (long)row0 * ldA : Bt + (long)row0 * ldB) + tkof;
    const int sw = (trow >> 1) & 3;
#pragma unroll
    for (int c = 0; c < TCH; ++c)
      toff[c] = trow * 32 + (((tpart * TCH + c) ^ sw) << 3);
  }

  auto t_apply = [&](int kk, short8x r0, short8x r1, int buf) {
    unsigned short* base = TRA ? &ldsA[buf][0] : &ldsB[buf][0];
    const short8x rr[2] = {r0, r1};
#pragma unroll
    for (int c = 0; c < TCH; ++c) {
      union { short8x v; unsigned short u[8]; } a0, w0;
      a0.v = rr[c];
      const float4* gp = (const float4*)(tg + kk + tkof + c * 8);
      const float4* bp = (const float4*)(tb + kk + tkof + c * 8);
      const float4 g0 = gp[0], g1 = gp[1];
      const float4 e0 = bp[0], e1 = bp[1];
      const float gg[8] = {g0.x, g0.y, g0.z, g0.w, g1.x, g1.y, g1.z, g1.w};
      const float ee[8] = {e0.x, e0.y, e0.z, e0.w, e1.x, e1.y, e1.z, e1.w};
#pragma unroll
      for (int u = 0; u < 8; ++u) {
        float y = (b2f(a0.u[u]) - t_mu) * t_rs * gg[u] + ee[u];
        y = y > 0.f ? y : tslope * y;
        w0.u[u] = f2b(y);
      }
      *(short8x*)&base[toff[c]] = w0.v;
    }
  };

  short8x tr0 = {}, tr1 = {};
  if constexpr (TR) {
    tr0 = *(const short8x*)(tsrc + 0);
    if constexpr (TCH == 2) tr1 = *(const short8x*)(tsrc + 8);
  }
  if constexpr (!TRA) { cp16(gA0, lA0[0]); cp16(gA1, lA1[0]); }
  if constexpr (!TRB) {
    cp16(gB0, lB0[0]);
    if constexpr (BN == 128) cp16(gB1, lB1[0]);
  }
  if constexpr (TR) t_apply(0, tr0, tr1, 0);

  f32x4 acc[4][JN] = {};
  int cur = 0;
  for (int k0 = 0; k0 < K; k0 += 32) {
    __syncthreads();
    const bool nxt = (k0 + 32 < K);
    if (nxt) {
      const int nk = k0 + 32;
      if constexpr (!TRA) { cp16(gA0 + nk, lA0[cur ^ 1]); cp16(gA1 + nk, lA1[cur ^ 1]); }
      if constexpr (!TRB) {
        cp16(gB0 + nk, lB0[cur ^ 1]);
        if constexpr (BN == 128) cp16(gB1 + nk, lB1[cur ^ 1]);
      }
      if constexpr (TR) {
        tr0 = *(const short8x*)(tsrc + nk);
        if constexpr (TCH == 2) tr1 = *(const short8x*)(tsrc + nk + 8);
      }
    }
    short8x af[4], bfr[JN];
#pragma unroll
    for (int i = 0; i < 4; ++i) {
      const int m = wm * 64 + i * 16 + lane15;
      af[i] = *(const short8x*)&ldsA[cur][m * 32 + ((q ^ ((m >> 1) & 3)) << 3)];
    }
#pragma unroll
    for (int j = 0; j < JN; ++j) {
      const int n = wn * (BN / 2) + j * 16 + lane15;
      bfr[j] = *(const short8x*)&ldsB[cur][n * 32 + ((q ^ ((n >> 1) & 3)) << 3)];
    }
#pragma unroll
    for (int i = 0; i < 4; ++i)
#pragma unroll
      for (int j = 0; j < JN; ++j)
        acc[i][j] = __builtin_amdgcn_mfma_f32_16x16x32_bf16(af[i], bfr[j], acc[i][j], 0, 0, 0);
    if (nxt) {
      if constexpr (TR) t_apply(k0 + 32, tr0, tr1, cur ^ 1);
    }
    cur ^= 1;
  }

  // epilogue (C/D layout: col=lane&15, row=(lane>>4)*4+reg)
  float* Yf = (float*)Yv;
  unsigned short* Yh = (unsigned short*)Yv;
  if constexpr (EPI == 0) Yf += (long)b * sY; else Yh += (long)b * sY;
  if constexpr (EPI == 5) Y2 += (long)b * sY;
  if constexpr (RES) res += (long)b * sR;
  float inv_[4];
  float kq0[4], kq1[4], kq2[4];
  float ssum[4][4], ssq[4][4];
#pragma unroll
  for (int i = 0; i < 4; ++i)
#pragma unroll
    for (int r = 0; r < 4; ++r) { ssum[i][r] = 0.f; ssq[i][r] = 0.f; }

#pragma unroll
  for (int i = 0; i < 4; ++i) {
    if constexpr (EPI == 4) {
#pragma unroll
      for (int r = 0; r < 4; ++r)
        inv_[r] = 1.f / ts1[(b & 7) * 1024 + m0 + wm * 64 + i * 16 + q * 4 + r];
    }
    if constexpr (EPI == 5) {
#pragma unroll
      for (int r = 0; r < 4; ++r) {
        const int m_g = m0 + wm * 64 + i * 16 + q * 4 + r;
        const float* pp = kpos + ((long)b * 1024 + m_g) * 3;
        kq0[r] = pp[0]; kq1[r] = pp[1]; kq2[r] = pp[2];
      }
    }
#pragma unroll
    for (int j = 0; j < JN; ++j) {
      const int n_g = n0 + wn * (BN / 2) + j * 16 + lane15;
      const float bc = BCOL ? bias[n_g] : 0.f;
      float pw0 = 0.f, pw1 = 0.f, pw2 = 0.f;
      if constexpr (EPI == 5) {
        pw0 = kpw[n_g * 3]; pw1 = kpw[n_g * 3 + 1]; pw2 = kpw[n_g * 3 + 2];
      }
#pragma unroll
      for (int r = 0; r < 4; ++r) {
        const int m_g = m0 + wm * 64 + i * 16 + q * 4 + r;
        float y = acc[i][j][r] * alpha;
        if constexpr (EPI == 4) y *= inv_[r];
        if constexpr (BCOL) y += bc;
        if constexpr (BROW) y += bias[m_g];
        if constexpr (RES) y += res[(long)m_g * ldY + n_g];
        if constexpr (EPI == 3) y = __expf(y);
        const long off = (long)m_g * ldY + n_g;
        if constexpr (EPI == 0) Yf[off] = y;
        else Yh[off] = f2b(y);
        if constexpr (EPI == 5)
          Y2[off] = f2b(y + pw0 * kq0[r] + pw1 * kq1[r] + pw2 * kq2[r]);
        if constexpr (EPI == 2 || EPI == 3 || EPI == 4) {
          ssum[i][r] += y; ssq[i][r] += y * y;
        }
      }
    }
  }
  if constexpr (EPI == 2 || EPI == 4) {
#pragma unroll
    for (int i = 0; i < 4; ++i)
#pragma unroll
      for (int r = 0; r < 4; ++r) {
        float s = ssum[i][r], q2 = ssq[i][r];
        s += __shfl_xor(s, 1); q2 += __shfl_xor(q2, 1);
        s += __shfl_xor(s, 2); q2 += __shfl_xor(q2, 2);
        s += __shfl_xor(s, 4); q2 += __shfl_xor(q2, 4);
        s += __shfl_xor(s, 8); q2 += __shfl_xor(q2, 8);
        if (lane15 == 0) {
          const int ridx = (b & 7) * 1024 + m0 + wm * 64 + i * 16 + q * 4 + r;
          atomicAdd(&os1[ridx], s);
          atomicAdd(&os2[ridx], q2);
        }
      }
  } else if constexpr (EPI == 3) {
#pragma unroll
    for (int i = 0; i < 4; ++i)
#pragma unroll
      for (int r = 0; r < 4; ++r) {
        float s = ssum[i][r];
        s += __shfl_xor(s, 1);
        s += __shfl_xor(s, 2);
        s += __shfl_xor(s, 4);
        s += __shfl_xor(s, 8);
        if (lane15 == 0) {
          const int ridx = (b & 7) * 1024 + m0 + wm * 64 + i * 16 + q * 4 + r;
          atomicAdd(&os1[ridx], s);
        }
      }
  }
}

// ===========================================================================
// Launch
// ===========================================================================
extern "C" void kernel_launch(void* const* d_in, const int* in_sizes, int n_in,
                              void* d_out, int out_size, void* d_ws,
                              size_t ws_size, hipStream_t stream) {
  const float* l1 = (const float*)d_in[0];
  const float* xyz1 = (const float*)d_in[1];
  const float* l2 = (const float*)d_in[2];
  const float* xyz2 = (const float*)d_in[3];
  const float* q1w = (const float*)d_in[4];
  const float* k1w = (const float*)d_in[5];
  const float* mlp_w1 = (const float*)d_in[6];
  const float* mlp_b1 = (const float*)d_in[7];
  const float* mlp_g1 = (const float*)d_in[8];
  const float* mlp_be1 = (const float*)d_in[9];
  const float* mlp_w2 = (const float*)d_in[10];
  const float* mlp_b2 = (const float*)d_in[11];
  const float* qw = (const float*)d_in[12];
  const float* kw = (const float*)d_in[13];
  const float* vw = (const float*)d_in[14];
  const float* posw = (const float*)d_in[15];
  const float* norm_g = (const float*)d_in[16];
  const float* norm_b = (const float*)d_in[17];
  const float* m1_w1 = (const float*)d_in[18];
  const float* m1_b1 = (const float*)d_in[19];
  const float* m1_g = (const float*)d_in[20];
  const float* m1_be = (const float*)d_in[21];
  const float* m1_w2 = (const float*)d_in[22];
  const float* m1_b2 = (const float*)d_in[23];

  char* ws = (char*)d_ws;
  const long MiB = 1048576;
  unsigned short* wb_mlp_w1 = (unsigned short*)(ws + 0);
  unsigned short* wb_mlp_w2 = (unsigned short*)(ws + 131072);
  unsigned short* wb_qw = (unsigned short*)(ws + 393216);
  unsigned short* wb_kw = (unsigned short*)(ws + 917504);
  unsigned short* wb_vw = (unsigned short*)(ws + 1441792);
  unsigned short* wb_m1w1 = (unsigned short*)(ws + 1966080);
  unsigned short* wb_m1w2 = (unsigned short*)(ws + 2490368);
  float* scores = (float*)(ws + 2752512);   // 128 KB
  int* idxb = (int*)(ws + 2891776);         // 32 KB
  float* p1selT = (float*)(ws + 2924544);   // 96 KB
  float* q1v = (float*)(ws + 3022848);      // 16 KB
  // zeroed region [3399680, 3637248): wvec (8 KB) + stats (7 x 32 KB)
  float* wvec = (float*)(ws + 3399680);
  float* rowsum = (float*)(ws + 3407872);
  float* h1_s1 = (float*)(ws + 3440640);
  float* h1_s2 = (float*)(ws + 3473408);
  float* o_s1 = (float*)(ws + 3506176);
  float* o_s2 = (float*)(ws + 3538944);
  float* g1_s1 = (float*)(ws + 3571712);
  float* g1_s2 = (float*)(ws + 3604480);
  // big buffers
  unsigned short* l1selT = (unsigned short*)(ws + 4 * MiB);
  unsigned short* h1 = (unsigned short*)(ws + 8 * MiB);
  unsigned short* x2T = (unsigned short*)(ws + 12 * MiB);
  unsigned short* qinT = (unsigned short*)(ws + 20 * MiB);
  unsigned short* kinT = (unsigned short*)(ws + 28 * MiB);   // contiguous w/ qinT
  float* l2T = (float*)(ws + 36 * MiB);
  unsigned short* qT = (unsigned short*)(ws + 52 * MiB);
  unsigned short* kT = (unsigned short*)(ws + 60 * MiB);     // contiguous w/ qT
  unsigned short* vbf = (unsigned short*)(ws + 68 * MiB);
  unsigned short* pbuf = (unsigned short*)(ws + 76 * MiB);
  unsigned short* obuf = (unsigned short*)(ws + 92 * MiB);
  unsigned short* g1buf = (unsigned short*)(ws + 100 * MiB);
  float* outp = (float*)d_out;

  const float inv_scale = 1.0f / sqrtf(512.0f);
  const long T256 = 1024L * 256, T512 = 1024L * 512, T1024 = 1024L * 1024;

  hipMemsetAsync(ws + 3399680, 0, 237568, stream);

  prep_kernel<<<dim3(1024, 9), 256, 0, stream>>>(
      mlp_w1, mlp_w2, qw, kw, vw, m1_w1, m1_w2,
      wb_mlp_w1, wb_mlp_w2, wb_qw, wb_kw, wb_vw, wb_m1w1, wb_m1w2,
      l1, q1w, q1v, l2, xyz2, posw, qinT, l2T);
  selB_kernel<<<dim3(8, 8), 256, 0, stream>>>(k1w, q1v, wvec);
  sel_scores_kernel<<<dim3(16, 8), 256, 0, stream>>>(l1, wvec, scores);
  topk_select_kernel<<<8, 256, 0, stream>>>(scores, idxb);
  gather_sel_kernel<<<dim3(16, 2, 8), 256, 0, stream>>>(l1, xyz1, idxb, l1selT, p1selT);

  // G1: h1 = l1selT·mlp_w1^T + b1 -> bf16 + LN stats
  gemm_u<64, 0, 0, true, false, false, 2><<<dim3(4, 8, 8), 256, 0, stream>>>(
      l1selT, T256, 256, wb_mlp_w1, 0, 256, 0, h1, T256, 256, mlp_b1,
      nullptr, 0, 256, 1.0f, nullptr, nullptr, nullptr, nullptr, 0.f,
      h1_s1, h1_s2, nullptr, nullptr, nullptr);
  // G2: x2T = relu(LN(h1))·mlp_w2^T + b2; also kinT = x2 + posw·p1sel (EPI 5)
  gemm_u<64, 1, 0, true, false, false, 5><<<dim3(8, 8, 8), 256, 0, stream>>>(
      h1, T256, 256, wb_mlp_w2, 0, 256, 0, x2T, T512, 512, mlp_b2,
      nullptr, 0, 256, 1.0f, h1_s1, h1_s2, mlp_g1, mlp_be1, 0.f,
      nullptr, nullptr, p1selT, posw, kinT);

  // Gqk: z 0..7 -> qT = qinT·qw^T ; z 8..15 -> kT = kinT·kw^T
  gemm_u<64, 0, 0, false, false, false, 1><<<dim3(8, 8, 16), 256, 0, stream>>>(
      qinT, T512, 512, wb_qw, 0, 512, 262144, qT, T512, 512, nullptr,
      nullptr, 0, 512, 1.0f, nullptr, nullptr, nullptr, nullptr, 0.f,
      nullptr, nullptr, nullptr, nullptr, nullptr);
  // Gv: v[c][m] = vw·x2T^T
  gemm_u<64, 0, 0, false, false, false, 1><<<dim3(16, 4, 8), 256, 0, stream>>>(
      wb_vw, 0, 512, x2T, T512, 512, 0, vbf, T512, 1024, nullptr,
      nullptr, 0, 512, 1.0f, nullptr, nullptr, nullptr, nullptr, 0.f,
      nullptr, nullptr, nullptr, nullptr, nullptr);

  // G7: p = exp(qT·kT^T/scale) -> bf16 + rowsum
  gemm_u<64, 0, 0, false, false, false, 3><<<dim3(16, 8, 8), 256, 0, stream>>>(
      qT, T512, 512, kT, T512, 512, 0, pbuf, T1024, 1024, nullptr,
      nullptr, 0, 512, inv_scale, nullptr, nullptr, nullptr, nullptr, 0.f,
      rowsum, nullptr, nullptr, nullptr, nullptr);
  // G8: o = (p·v^T)/rowsum + l2T -> bf16 + LN stats
  gemm_u<64, 0, 0, false, false, true, 4><<<dim3(8, 8, 8), 256, 0, stream>>>(
      pbuf, T1024, 1024, vbf, T512, 1024, 0, obuf, T512, 512, nullptr,
      l2T, T512, 1024, 1.0f, rowsum, nullptr, nullptr, nullptr, 0.f,
      o_s1, o_s2, nullptr, nullptr, nullptr);
  // G9: g1 = leaky(LN(o))·m1_w1^T + b1 -> bf16 + LN stats (A transformed)
  gemm_u<64, 1, 0, true, false, false, 2><<<dim3(8, 8, 8), 256, 0, stream>>>(
      obuf, T512, 512, wb_m1w1, 0, 512, 0, g1buf, T512, 512, m1_b1,
      nullptr, 0, 512, 1.0f, o_s1, o_s2, norm_g, norm_b, 0.01f,
      g1_s1, g1_s2, nullptr, nullptr, nullptr);
  // G10: out = m1_w2·relu(LN(g1))^T + b2 -> f32 d_out (B transformed)
  gemm_u<64, 0, 1, false, true, false, 0><<<dim3(16, 2, 8), 256, 0, stream>>>(
      wb_m1w2, 0, 512, g1buf, T512, 512, 0, outp, 256L * 1024, 1024, m1_b2,
      nullptr, 0, 512, 1.0f, g1_s1, g1_s2, m1_g, m1_be, 0.f,
      nullptr, nullptr, nullptr, nullptr, nullptr);
}